// Round 1
// baseline (1230.556 us; speedup 1.0000x reference)
//
#include <hip/hip_runtime.h>

#define NDIM 2048
#define LEV  256
#define KS   16

// ---------------------------------------------------------------------------
// Build right = U_{L-1} ... U_0 column-by-column. Each column j evolves
// independently: col <- U_l col only touches col[sel_l] and reads col[sel_l].
// One wave (64 threads) handles 4 columns held in LDS (stride 2052 floats:
// 2052 % 32 == 4, so the 4 column bases land on distinct banks).
// ---------------------------------------------------------------------------
__global__ __launch_bounds__(64)
void build_right_k(const float* __restrict__ O_all, const int* __restrict__ sel,
                   float* __restrict__ Rout) {
    __shared__ float cols[4 * 2052];
    const int lane = threadIdx.x;       // 0..63
    const int c    = lane >> 4;         // column slot 0..3
    const int i    = lane & 15;         // output row 0..15
    const int col0 = blockIdx.x * 4;
    float* mycol = &cols[c * 2052];

    for (int v = lane; v < 4 * 2052; v += 64) cols[v] = 0.0f;
    __syncthreads();
    if (lane < 4) cols[lane * 2052 + col0 + lane] = 1.0f;   // e_j
    __syncthreads();

    for (int l = 0; l < LEV; ++l) {
        const int* ip = sel + l * KS;
        int idx[KS];
        #pragma unroll
        for (int k = 0; k < KS; ++k) idx[k] = ip[k];

        const float4* o4 = (const float4*)(O_all + (size_t)l * (KS * KS) + i * KS);
        float4 oa = o4[0], ob = o4[1], oc = o4[2], od = o4[3];
        float o[KS] = {oa.x, oa.y, oa.z, oa.w, ob.x, ob.y, ob.z, ob.w,
                       oc.x, oc.y, oc.z, oc.w, od.x, od.y, od.z, od.w};

        float r = 0.0f;
        #pragma unroll
        for (int k = 0; k < KS; ++k) r += o[k] * mycol[idx[k]];
        __syncthreads();                 // all gathers done before any scatter
        mycol[idx[i]] = r;
        __syncthreads();
    }

    // R row-major: R[row][col0+c] = cols[c][row]
    for (int v = lane; v < 4 * 2048; v += 64) {
        const int row = v >> 2;
        const int cc  = v & 3;
        Rout[(size_t)row * NDIM + col0 + cc] = cols[cc * 2052 + row];
    }
}

// ---------------------------------------------------------------------------
// active flags: 1 everywhere, 0 at wav_idx
// ---------------------------------------------------------------------------
__global__ void init_active_k(const int* __restrict__ wav, float* __restrict__ act, int Lw) {
    for (int t = threadIdx.x; t < NDIM; t += 256) act[t] = 1.0f;
    __syncthreads();
    for (int t = threadIdx.x; t < Lw; t += 256) act[wav[t]] = 0.0f;
}

// ---------------------------------------------------------------------------
// fp32 GEMM, C = opA(A) * opB(B), 2048^3. TA: opA[i,k]=A[k,i]. TB: opB[k,j]=B[j,k].
// 128x128x16 tile, 256 threads, 8x8 micro-tile. MASKED: D-epilogue
// (keep diag; off-diag scaled by act[i]*act[j]).
// ---------------------------------------------------------------------------
template<int TA, int TB, int MASKED>
__global__ __launch_bounds__(256)
void gemm_t(const float* __restrict__ Ag, const float* __restrict__ Bg,
            float* __restrict__ Cg, const float* __restrict__ act) {
    constexpr int BM = 128, BN = 128, BK = 16;
    __shared__ float As[BK][BM + 4];
    __shared__ float Bs[BK][BN + 4];
    const int tid = threadIdx.x;
    const int bx = blockIdx.x & 15;
    const int by = blockIdx.x >> 4;
    const int i0 = by * BM, j0 = bx * BN;
    const int tx = tid & 15, ty = tid >> 4;

    float acc[8][8];
    #pragma unroll
    for (int r = 0; r < 8; ++r)
        #pragma unroll
        for (int cc = 0; cc < 8; ++cc) acc[r][cc] = 0.0f;

    for (int k0 = 0; k0 < NDIM; k0 += BK) {
        if (TA == 0) {  // As[kk][ii] = A[i0+ii][k0+kk]  (transpose into LDS)
            const int ii = tid >> 1, kb = (tid & 1) * 8;
            const float* src = Ag + (size_t)(i0 + ii) * NDIM + k0 + kb;
            float4 v0 = *(const float4*)src;
            float4 v1 = *(const float4*)(src + 4);
            As[kb + 0][ii] = v0.x; As[kb + 1][ii] = v0.y;
            As[kb + 2][ii] = v0.z; As[kb + 3][ii] = v0.w;
            As[kb + 4][ii] = v1.x; As[kb + 5][ii] = v1.y;
            As[kb + 6][ii] = v1.z; As[kb + 7][ii] = v1.w;
        } else {        // As[kk][ii] = A[k0+kk][i0+ii]  (direct rows)
            const int kk = tid >> 4, ib = (tid & 15) * 8;
            const float* src = Ag + (size_t)(k0 + kk) * NDIM + i0 + ib;
            *(float4*)&As[kk][ib]     = *(const float4*)src;
            *(float4*)&As[kk][ib + 4] = *(const float4*)(src + 4);
        }
        if (TB == 0) {  // Bs[kk][jj] = B[k0+kk][j0+jj]  (direct rows)
            const int kk = tid >> 4, jb = (tid & 15) * 8;
            const float* src = Bg + (size_t)(k0 + kk) * NDIM + j0 + jb;
            *(float4*)&Bs[kk][jb]     = *(const float4*)src;
            *(float4*)&Bs[kk][jb + 4] = *(const float4*)(src + 4);
        } else {        // Bs[kk][jj] = B[j0+jj][k0+kk]  (transpose into LDS)
            const int jj = tid >> 1, kb = (tid & 1) * 8;
            const float* src = Bg + (size_t)(j0 + jj) * NDIM + k0 + kb;
            float4 v0 = *(const float4*)src;
            float4 v1 = *(const float4*)(src + 4);
            Bs[kb + 0][jj] = v0.x; Bs[kb + 1][jj] = v0.y;
            Bs[kb + 2][jj] = v0.z; Bs[kb + 3][jj] = v0.w;
            Bs[kb + 4][jj] = v1.x; Bs[kb + 5][jj] = v1.y;
            Bs[kb + 6][jj] = v1.z; Bs[kb + 7][jj] = v1.w;
        }
        __syncthreads();
        #pragma unroll
        for (int kk = 0; kk < BK; ++kk) {
            float4 a0 = *(const float4*)&As[kk][ty * 8];
            float4 a1 = *(const float4*)&As[kk][ty * 8 + 4];
            float4 b0 = *(const float4*)&Bs[kk][tx * 8];
            float4 b1 = *(const float4*)&Bs[kk][tx * 8 + 4];
            float av[8] = {a0.x, a0.y, a0.z, a0.w, a1.x, a1.y, a1.z, a1.w};
            float bv[8] = {b0.x, b0.y, b0.z, b0.w, b1.x, b1.y, b1.z, b1.w};
            #pragma unroll
            for (int r = 0; r < 8; ++r)
                #pragma unroll
                for (int cc = 0; cc < 8; ++cc)
                    acc[r][cc] += av[r] * bv[cc];
        }
        __syncthreads();
    }

    #pragma unroll
    for (int r = 0; r < 8; ++r) {
        const int gi = i0 + ty * 8 + r;
        float* dst = Cg + (size_t)gi * NDIM + j0 + tx * 8;
        float vals[8];
        #pragma unroll
        for (int cc = 0; cc < 8; ++cc) vals[cc] = acc[r][cc];
        if (MASKED) {
            const float ai = act[gi];
            #pragma unroll
            for (int cc = 0; cc < 8; ++cc) {
                const int gj = j0 + tx * 8 + cc;
                if (gi != gj) vals[cc] *= ai * act[gj];
            }
        }
        *(float4*)dst       = make_float4(vals[0], vals[1], vals[2], vals[3]);
        *(float4*)(dst + 4) = make_float4(vals[4], vals[5], vals[6], vals[7]);
    }
}

// ---------------------------------------------------------------------------
// A_rec = R^T D R,  D = mask ⊙ (R A R^T),  right = R
// d_out layout: [A_rec | R | D], each 2048^2 floats.
// Temps: T = R*A lives in the A_rec slot (dead before final write);
//        T2 = R^T*D in d_ws (+16KB offset past active flags).
// ---------------------------------------------------------------------------
extern "C" void kernel_launch(void* const* d_in, const int* in_sizes, int n_in,
                              void* d_out, int out_size, void* d_ws, size_t ws_size,
                              hipStream_t stream) {
    const float* A     = (const float*)d_in[0];
    const float* O_all = (const float*)d_in[1];
    const int*   sel   = (const int*)d_in[2];
    const int*   wav   = (const int*)d_in[3];
    const int    Lw    = in_sizes[3];

    const size_t NN2 = (size_t)NDIM * NDIM;
    float* Arec = (float*)d_out;
    float* R    = Arec + NN2;
    float* D    = Arec + 2 * NN2;
    float* T    = Arec;                       // temp in A_rec slot
    float* act  = (float*)d_ws;               // 2048 floats
    float* T2   = (float*)d_ws + 4096;        // 16KB offset; needs ws >= 16MB+16KB

    init_active_k<<<1, 256, 0, stream>>>(wav, act, Lw);
    build_right_k<<<NDIM / 4, 64, 0, stream>>>(O_all, sel, R);

    gemm_t<0, 0, 0><<<256, 256, 0, stream>>>(R,  A, T,    nullptr); // T  = R*A
    gemm_t<0, 1, 1><<<256, 256, 0, stream>>>(T,  R, D,    act);     // D  = mask⊙(T*R^T)
    gemm_t<1, 0, 0><<<256, 256, 0, stream>>>(R,  D, T2,   nullptr); // T2 = R^T*D
    gemm_t<0, 0, 0><<<256, 256, 0, stream>>>(T2, R, Arec, nullptr); // A_rec = T2*R
}

// Round 2
// 856.709 us; speedup vs baseline: 1.4364x; 1.4364x over previous
//
#include <hip/hip_runtime.h>

#define N 2048
#define LEV 256
#define KS 16

typedef __attribute__((ext_vector_type(8))) short bfx8;
typedef __attribute__((ext_vector_type(4))) float fx4;
typedef unsigned short u16;
typedef unsigned int u32;

static const size_t NN = (size_t)N * N;

__device__ inline u16 bf16_rne(float f) {
    u32 u = __builtin_bit_cast(u32, f);
    u32 r = (u + 0x7FFFu + ((u >> 16) & 1u)) >> 16;
    return (u16)r;
}
__device__ inline float bf16_f(u16 h) {
    u32 u = ((u32)h) << 16;
    return __builtin_bit_cast(float, u);
}

// ---------------------------------------------------------------------------
// build right = U_{L-1}...U_0, column-independent evolution in LDS (unchanged).
// ---------------------------------------------------------------------------
__global__ __launch_bounds__(64)
void build_right_k(const float* __restrict__ O_all, const int* __restrict__ sel,
                   float* __restrict__ Rout) {
    __shared__ float cols[4 * 2052];
    const int lane = threadIdx.x;
    const int c    = lane >> 4;
    const int i    = lane & 15;
    const int col0 = blockIdx.x * 4;
    float* mycol = &cols[c * 2052];

    for (int v = lane; v < 4 * 2052; v += 64) cols[v] = 0.0f;
    __syncthreads();
    if (lane < 4) cols[lane * 2052 + col0 + lane] = 1.0f;
    __syncthreads();

    for (int l = 0; l < LEV; ++l) {
        const int* ip = sel + l * KS;
        int idx[KS];
        #pragma unroll
        for (int k = 0; k < KS; ++k) idx[k] = ip[k];

        const float4* o4 = (const float4*)(O_all + (size_t)l * (KS * KS) + i * KS);
        float4 oa = o4[0], ob = o4[1], oc = o4[2], od = o4[3];
        float o[KS] = {oa.x, oa.y, oa.z, oa.w, ob.x, ob.y, ob.z, ob.w,
                       oc.x, oc.y, oc.z, oc.w, od.x, od.y, od.z, od.w};

        float r = 0.0f;
        #pragma unroll
        for (int k = 0; k < KS; ++k) r += o[k] * mycol[idx[k]];
        __syncthreads();
        mycol[idx[i]] = r;
        __syncthreads();
    }

    for (int v = lane; v < 4 * 2048; v += 64) {
        const int row = v >> 2;
        const int cc  = v & 3;
        Rout[(size_t)row * N + col0 + cc] = cols[cc * 2052 + row];
    }
}

// ---------------------------------------------------------------------------
// split fp32 matrix -> bf16 hi/lo planes (row-major, same layout)
// ---------------------------------------------------------------------------
__global__ __launch_bounds__(256)
void split_plain_k(const float* __restrict__ src, u16* __restrict__ dh) {
    u16* dl = dh + NN;
    size_t p = ((size_t)blockIdx.x * 256 + threadIdx.x) * 8;
    float4 v0 = *(const float4*)(src + p);
    float4 v1 = *(const float4*)(src + p + 4);
    float vv[8] = {v0.x, v0.y, v0.z, v0.w, v1.x, v1.y, v1.z, v1.w};
    bfx8 hs, ls;
    #pragma unroll
    for (int i = 0; i < 8; ++i) {
        u16 h = bf16_rne(vv[i]);
        hs[i] = (short)h;
        ls[i] = (short)bf16_rne(vv[i] - bf16_f(h));
    }
    *(bfx8*)(dh + p) = hs;
    *(bfx8*)(dl + p) = ls;
}

// ---------------------------------------------------------------------------
// split R into R2 (hi/lo) and RT2 = split(R^T) (hi/lo) via 64x64 LDS tiles
// ---------------------------------------------------------------------------
__global__ __launch_bounds__(256)
void split_rt_k(const float* __restrict__ R, u16* __restrict__ r2h, u16* __restrict__ rth) {
    __shared__ float t[64][65];
    u16* r2l = r2h + NN;
    u16* rtl = rth + NN;
    const int r0 = (blockIdx.x >> 5) * 64, c0 = (blockIdx.x & 31) * 64;
    #pragma unroll
    for (int i = 0; i < 16; ++i) {
        int q = i * 256 + threadIdx.x;
        int rr = q >> 6, cc = q & 63;
        t[rr][cc] = R[(size_t)(r0 + rr) * N + c0 + cc];
    }
    __syncthreads();
    #pragma unroll
    for (int i = 0; i < 16; ++i) {
        int q = i * 256 + threadIdx.x;
        int rr = q >> 6, cc = q & 63;
        float v = t[rr][cc];
        u16 h = bf16_rne(v);
        size_t po = (size_t)(r0 + rr) * N + c0 + cc;
        r2h[po] = h;
        r2l[po] = bf16_rne(v - bf16_f(h));
        float w = t[cc][rr];                    // = R[r0+cc][c0+rr]
        u16 h2 = bf16_rne(w);
        size_t pt = (size_t)(c0 + rr) * N + r0 + cc;  // RT2[c0+rr][r0+cc]
        rth[pt] = h2;
        rtl[pt] = bf16_rne(w - bf16_f(h2));
    }
}

// ---------------------------------------------------------------------------
// D fp32 = hi + lo (planes previously copied to ws)
// ---------------------------------------------------------------------------
__global__ __launch_bounds__(256)
void unsplit_k(const u16* __restrict__ hi, float* __restrict__ dst) {
    const u16* lo = hi + NN;
    size_t p = ((size_t)blockIdx.x * 256 + threadIdx.x) * 8;
    bfx8 hs = *(const bfx8*)(hi + p);
    bfx8 ls = *(const bfx8*)(lo + p);
    float4 o0, o1;
    o0.x = bf16_f((u16)hs[0]) + bf16_f((u16)ls[0]);
    o0.y = bf16_f((u16)hs[1]) + bf16_f((u16)ls[1]);
    o0.z = bf16_f((u16)hs[2]) + bf16_f((u16)ls[2]);
    o0.w = bf16_f((u16)hs[3]) + bf16_f((u16)ls[3]);
    o1.x = bf16_f((u16)hs[4]) + bf16_f((u16)ls[4]);
    o1.y = bf16_f((u16)hs[5]) + bf16_f((u16)ls[5]);
    o1.z = bf16_f((u16)hs[6]) + bf16_f((u16)ls[6]);
    o1.w = bf16_f((u16)hs[7]) + bf16_f((u16)ls[7]);
    *(float4*)(dst + p)     = o0;
    *(float4*)(dst + p + 4) = o1;
}

// ---------------------------------------------------------------------------
// C = X * Y^T via 3-term bf16 split MFMA.
// X, Y given as hi-plane pointers (lo = +NN), row-major [dim][k].
// C[i][j] = sum_k X[i][k]*Y[j][k].
// 128x128 tile, BK=64, 4 waves of 64x64, mfma_f32_16x16x32_bf16.
// SPLIT_OUT: write C as hi/lo planes; else fp32.
// MASKED: off-diagonal scaled by act(i)*act(j), act=0 on wav indices.
// ---------------------------------------------------------------------------
template<int MASKED, int SPLIT_OUT>
__global__ __launch_bounds__(256, 1)
void gemm_bf3(const u16* __restrict__ Xp, const u16* __restrict__ Yp,
              float* __restrict__ Cf, u16* __restrict__ Cs,
              const int* __restrict__ wav, int Lw) {
    constexpr int LDR = 72;   // LDS row stride (shorts): 64 + 8 pad
    __shared__ __align__(16) u16 As[2][128 * LDR];
    __shared__ __align__(16) u16 Bs[2][128 * LDR];
    __shared__ float rowf[128], colf[128];

    const int tid = threadIdx.x;
    const int bx = blockIdx.x & 15;
    const int by = blockIdx.x >> 4;
    const int i0 = by * 128, j0 = bx * 128;
    const int lane = tid & 63, wid = tid >> 6;
    const int wm = (wid >> 1) * 64, wn = (wid & 1) * 64;
    const int fr = lane & 15;
    const int fk = (lane >> 4) * 8;

    if (MASKED) {
        if (tid < 128) rowf[tid] = 1.0f; else colf[tid - 128] = 1.0f;
        __syncthreads();
        for (int t = tid; t < Lw; t += 256) {
            int w = wav[t];
            int dr = w - i0; if (0 <= dr && dr < 128) rowf[dr] = 0.0f;
            int dc = w - j0; if (0 <= dc && dc < 128) colf[dc] = 0.0f;
        }
        // covered by first main-loop barrier
    }

    fx4 acc[4][4];
    #pragma unroll
    for (int m = 0; m < 4; ++m)
        #pragma unroll
        for (int n = 0; n < 4; ++n)
            acc[m][n] = (fx4)0.0f;

    const u16* Xh = Xp; const u16* Xl = Xp + NN;
    const u16* Yh = Yp; const u16* Yl = Yp + NN;
    const int srow = tid >> 3;            // base row, +32 per chunk
    const int soff = (tid & 7) * 8;       // short offset within 64-wide row

    float4 pf[16];
    #define LOADT(k0)                                                            \
        { _Pragma("unroll")                                                      \
          for (int c = 0; c < 4; ++c) {                                          \
            int r = srow + 32 * c;                                               \
            pf[c]      = *(const float4*)(Xh + (size_t)(i0 + r) * N + (k0) + soff); \
            pf[4 + c]  = *(const float4*)(Xl + (size_t)(i0 + r) * N + (k0) + soff); \
            pf[8 + c]  = *(const float4*)(Yh + (size_t)(j0 + r) * N + (k0) + soff); \
            pf[12 + c] = *(const float4*)(Yl + (size_t)(j0 + r) * N + (k0) + soff); \
          } }

    LOADT(0)
    constexpr int NT = N / 64;
    for (int kt = 0; kt < NT; ++kt) {
        #pragma unroll
        for (int c = 0; c < 4; ++c) {
            int r = srow + 32 * c;
            *(float4*)&As[0][r * LDR + soff] = pf[c];
            *(float4*)&As[1][r * LDR + soff] = pf[4 + c];
            *(float4*)&Bs[0][r * LDR + soff] = pf[8 + c];
            *(float4*)&Bs[1][r * LDR + soff] = pf[12 + c];
        }
        __syncthreads();
        if (kt + 1 < NT) LOADT((kt + 1) * 64)
        #pragma unroll
        for (int s = 0; s < 2; ++s) {
            bfx8 ah[4], al[4];
            #pragma unroll
            for (int m = 0; m < 4; ++m) {
                const int ar = (wm + m * 16 + fr) * LDR + s * 32 + fk;
                ah[m] = *(const bfx8*)&As[0][ar];
                al[m] = *(const bfx8*)&As[1][ar];
            }
            #pragma unroll
            for (int n = 0; n < 4; ++n) {
                const int br = (wn + n * 16 + fr) * LDR + s * 32 + fk;
                bfx8 bh = *(const bfx8*)&Bs[0][br];
                bfx8 bl = *(const bfx8*)&Bs[1][br];
                #pragma unroll
                for (int m = 0; m < 4; ++m) {
                    acc[m][n] = __builtin_amdgcn_mfma_f32_16x16x32_bf16(ah[m], bh, acc[m][n], 0, 0, 0);
                    acc[m][n] = __builtin_amdgcn_mfma_f32_16x16x32_bf16(ah[m], bl, acc[m][n], 0, 0, 0);
                    acc[m][n] = __builtin_amdgcn_mfma_f32_16x16x32_bf16(al[m], bh, acc[m][n], 0, 0, 0);
                }
            }
        }
        __syncthreads();
    }

    const int crow0 = (lane >> 4) * 4;
    #pragma unroll
    for (int m = 0; m < 4; ++m) {
        #pragma unroll
        for (int n = 0; n < 4; ++n) {
            #pragma unroll
            for (int r = 0; r < 4; ++r) {
                const int li = wm + m * 16 + crow0 + r;
                const int lj = wn + n * 16 + fr;
                float v = acc[m][n][r];
                if (MASKED) {
                    if (i0 + li != j0 + lj) v *= rowf[li] * colf[lj];
                }
                const size_t off = (size_t)(i0 + li) * N + j0 + lj;
                if (SPLIT_OUT) {
                    u16 h = bf16_rne(v);
                    Cs[off]      = h;
                    Cs[NN + off] = bf16_rne(v - bf16_f(h));
                } else {
                    Cf[off] = v;
                }
            }
        }
    }
}

// ---------------------------------------------------------------------------
// Schedule (all products are X * Y^T on split planes):
//   A2 = split(A)            -> D slot (scratch until D written)
//   R  = build_right         -> R slot (output)
//   R2 = split(R), RT2 = split(R^T) -> ws[0:16M), ws[16M:32M)
//   Ts   = R2 ⊛ A2^T         -> Arec slot (split)     [T = R A, A sym]
//   D2   = mask(Ts ⊛ R2^T)   -> D slot    (split)     [D = T R^T]
//   T2s  = RT2 ⊛ D2^T        -> ws[0:16M) (split)     [T2 = R^T D, D sym]
//   Arec = T2s ⊛ RT2^T       -> Arec slot (fp32)      [Arec = T2 R]
//   copy D2 -> ws[0:16M); D fp32 = hi+lo -> D slot
// ws requirement: 32 MB.
// ---------------------------------------------------------------------------
extern "C" void kernel_launch(void* const* d_in, const int* in_sizes, int n_in,
                              void* d_out, int out_size, void* d_ws, size_t ws_size,
                              hipStream_t stream) {
    const float* A     = (const float*)d_in[0];
    const float* O_all = (const float*)d_in[1];
    const int*   sel   = (const int*)d_in[2];
    const int*   wav   = (const int*)d_in[3];
    const int    Lw    = in_sizes[3];

    float* Arec = (float*)d_out;
    float* Rslt = Arec + NN;
    float* Dslt = Arec + 2 * NN;

    u16* A2  = (u16*)Dslt;                       // scratch in D slot
    u16* Ts  = (u16*)Arec;                       // scratch in Arec slot
    u16* D2  = (u16*)Dslt;
    u16* R2  = (u16*)d_ws;                       // ws[0, 16M)
    u16* RT2 = (u16*)((char*)d_ws + 2 * NN * sizeof(u16));  // ws[16M, 32M)
    u16* T2s = (u16*)d_ws;                       // reuses R2 region after G2

    split_plain_k<<<NN / (256 * 8), 256, 0, stream>>>(A, A2);
    build_right_k<<<N / 4, 64, 0, stream>>>(O_all, sel, Rslt);
    split_rt_k<<<(N / 64) * (N / 64), 256, 0, stream>>>(Rslt, R2, RT2);

    gemm_bf3<0, 1><<<256, 256, 0, stream>>>(R2,  A2,  nullptr, Ts,  nullptr, 0);
    gemm_bf3<1, 1><<<256, 256, 0, stream>>>(Ts,  R2,  nullptr, D2,  wav, Lw);
    gemm_bf3<0, 1><<<256, 256, 0, stream>>>(RT2, D2,  nullptr, T2s, nullptr, 0);
    gemm_bf3<0, 0><<<256, 256, 0, stream>>>(T2s, RT2, Arec,    nullptr, nullptr, 0);

    hipMemcpyAsync(d_ws, Dslt, 2 * NN * sizeof(u16), hipMemcpyDeviceToDevice, stream);
    unsplit_k<<<NN / (256 * 8), 256, 0, stream>>>((u16*)d_ws, Dslt);
}